// Round 14
// baseline (111.727 us; speedup 1.0000x reference)
//
#include <hip/hip_runtime.h>
#include <hip/hip_bf16.h>
#include <stdint.h>

#define NI 256
#define NT 256
#define NL 25
#define NE 128
#define NHW 49
#define NTL (NT*NL)   // 6400

#define WAVES 8            // waves (=images) per match WG
#define CH_T 16            // texts per chunk
#define CH_TILES 25        // 16-row B tiles per chunk

typedef __attribute__((ext_vector_type(4))) int i32x4;

__device__ __forceinline__ int pack4(int q0, int q1, int q2, int q3) {
    return (q0 & 255) | ((q1 & 255) << 8) | ((q2 & 255) << 16) | ((q3 & 255) << 24);
}

// ---- Prep (identical to round 12) ----
__global__ __launch_bounds__(256) void prep_kernel(
    const float* __restrict__ emb, const int* __restrict__ text,
    const float* __restrict__ img,
    char* __restrict__ tf3, char* __restrict__ P2, char* __restrict__ P48,
    float* __restrict__ tfs, float* __restrict__ pscale)
{
    __shared__ float tile[NE * NHW];
    __shared__ float red[256];
    const int bid = blockIdx.x;
    const int tid = threadIdx.x;

    if (bid < 400) {
        int r   = tid >> 4;
        int sub = tid & 15;
        int row = bid * 16 + r;
        int tok = text[row];
        const float4* e4 = reinterpret_cast<const float4*>(emb + (size_t)tok * NE + sub * 8);
        float4 f0 = e4[0], f1 = e4[1];
        float m = fmaxf(fmaxf(fmaxf(fabsf(f0.x), fabsf(f0.y)), fmaxf(fabsf(f0.z), fabsf(f0.w))),
                        fmaxf(fmaxf(fabsf(f1.x), fabsf(f1.y)), fmaxf(fabsf(f1.z), fabsf(f1.w))));
        m = fmaxf(m, __shfl_xor(m, 1));
        m = fmaxf(m, __shfl_xor(m, 2));
        m = fmaxf(m, __shfl_xor(m, 4));
        m = fmaxf(m, __shfl_xor(m, 8));
        float s = (m > 0.f) ? 127.f / m : 0.f;
        if (sub == 0) tfs[row] = m / 127.f;
        int q0 = __float2int_rn(f0.x * s), q1 = __float2int_rn(f0.y * s);
        int q2 = __float2int_rn(f0.z * s), q3 = __float2int_rn(f0.w * s);
        int q4 = __float2int_rn(f1.x * s), q5 = __float2int_rn(f1.y * s);
        int q6 = __float2int_rn(f1.z * s), q7 = __float2int_rn(f1.w * s);
        int2 o = make_int2(pack4(q0, q1, q2, q3), pack4(q4, q5, q6, q7));
        int kh  = sub >> 3;
        int lhi = (sub >> 1) & 3;
        size_t addr = ((size_t)(bid * 2 + kh) * 64 + lhi * 16 + r) * 16 + (sub & 1) * 8;
        *reinterpret_cast<int2*>(tf3 + addr) = o;
    } else {
        int i = bid - 400;
        const float4* src4 = reinterpret_cast<const float4*>(img + (size_t)i * NE * NHW);
        float4* tile4 = reinterpret_cast<float4*>(tile);
        for (int idx = tid; idx < NE * NHW / 4; idx += 256) tile4[idx] = src4[idx];
        __syncthreads();
        float lm = 0.f;
        for (int idx = tid; idx < NE * NHW; idx += 256) lm = fmaxf(lm, fabsf(tile[idx]));
        red[tid] = lm;
        __syncthreads();
        #pragma unroll
        for (int st = 128; st > 0; st >>= 1) {
            if (tid < st) red[tid] = fmaxf(red[tid], red[tid + st]);
            __syncthreads();
        }
        float pmax = red[0];
        float s = (pmax > 0.f) ? 127.f / pmax : 0.f;
        if (tid == 0) pscale[i] = pmax / 127.f;

        for (int idx = tid; idx < 384; idx += 256) {
            int f = idx >> 6, lane = idx & 63;
            int mt = f >> 1, kh = f & 1;
            int lr = lane & 15, lhi = lane >> 4;
            int p = mt * 16 + lr;
            int d[4];
            #pragma unroll
            for (int w = 0; w < 4; w++) {
                int e = kh * 64 + lhi * 16 + w * 4;
                d[w] = pack4(__float2int_rn(tile[(e + 0) * NHW + p] * s),
                             __float2int_rn(tile[(e + 1) * NHW + p] * s),
                             __float2int_rn(tile[(e + 2) * NHW + p] * s),
                             __float2int_rn(tile[(e + 3) * NHW + p] * s));
            }
            i32x4 o = { d[0], d[1], d[2], d[3] };
            *reinterpret_cast<i32x4*>(P2 + ((size_t)(i * 6 + f) * 64 + lane) * 16) = o;
        }
        if (tid < 8) {
            int kh = tid & 1, lhi = (tid >> 1) & 3;
            int g = i >> 3, lr0 = i & 7;
            int d[4];
            #pragma unroll
            for (int w = 0; w < 4; w++) {
                int e = kh * 64 + lhi * 16 + w * 4;
                d[w] = pack4(__float2int_rn(tile[(e + 0) * NHW + 48] * s),
                             __float2int_rn(tile[(e + 1) * NHW + 48] * s),
                             __float2int_rn(tile[(e + 2) * NHW + 48] * s),
                             __float2int_rn(tile[(e + 3) * NHW + 48] * s));
            }
            i32x4 o = { d[0], d[1], d[2], d[3] };
            *reinterpret_cast<i32x4*>(P48 + ((size_t)(g * 2 + kh) * 64 + lhi * 16 + lr0) * 16) = o;
        }
    }
}

// ---- Match body (r12), shared by real kernel and the 8x probe ----
__device__ __forceinline__ void match_body(
    int wgid,
    const char* __restrict__ tf3, const char* __restrict__ P2,
    const char* __restrict__ P48, const float* __restrict__ tfs,
    const float* __restrict__ pscale, const int* __restrict__ text_length,
    const float* __restrict__ logit_scale, float* __restrict__ out,
    int vals[WAVES][CH_TILES][64], int vals48[CH_TILES][128])
{
    const int ig   = wgid & 31;
    const int tq   = wgid >> 5;
    const int tid  = threadIdx.x;
    const int wave = tid >> 6;
    const int lane = tid & 63;
    const int lr   = lane & 15;
    const int lhi  = lane >> 4;

    const int img = ig * WAVES + wave;
    const i32x4* p2 = reinterpret_cast<const i32x4*>(P2) + (size_t)img * 6 * 64 + lane;
    i32x4 pf[6];
    #pragma unroll
    for (int f = 0; f < 6; f++) pf[f] = p2[f * 64];
    #pragma unroll
    for (int f = 0; f < 6; f++) asm volatile("" : "+v"(pf[f]));

    const i32x4* p48 = reinterpret_cast<const i32x4*>(P48) + (size_t)ig * 2 * 64 + lane;

    i32x4 zc = { 0, 0, 0, 0 };
    asm volatile("" : "+v"(zc));

    const char* tb = tf3 + (size_t)tq * CH_TILES * 2048 + lane * 16;

    auto loadT = [&](i32x4* T, int jl) {
        T[0] = *reinterpret_cast<const i32x4*>(tb + jl * 2048);
        T[1] = *reinterpret_cast<const i32x4*>(tb + jl * 2048 + 1024);
    };

    auto imax = [](int a, int b) { return a > b ? a : b; };

    auto compute = [&](const i32x4* T, int jl) {
        __builtin_amdgcn_s_setprio(1);
        i32x4 a0 = __builtin_amdgcn_mfma_i32_16x16x64_i8(pf[0], T[0], zc, 0, 0, 0);
        i32x4 a1 = __builtin_amdgcn_mfma_i32_16x16x64_i8(pf[2], T[0], zc, 0, 0, 0);
        i32x4 a2 = __builtin_amdgcn_mfma_i32_16x16x64_i8(pf[4], T[0], zc, 0, 0, 0);
        a0 = __builtin_amdgcn_mfma_i32_16x16x64_i8(pf[1], T[1], a0, 0, 0, 0);
        a1 = __builtin_amdgcn_mfma_i32_16x16x64_i8(pf[3], T[1], a1, 0, 0, 0);
        a2 = __builtin_amdgcn_mfma_i32_16x16x64_i8(pf[5], T[1], a2, 0, 0, 0);
        if ((jl & 7) == wave) {
            i32x4 d = __builtin_amdgcn_mfma_i32_16x16x64_i8(p48[0],  T[0], zc, 0, 0, 0);
            d = __builtin_amdgcn_mfma_i32_16x16x64_i8(p48[64], T[1], d, 0, 0, 0);
            __builtin_amdgcn_s_setprio(0);
            if (lhi < 2) {
                #pragma unroll
                for (int r = 0; r < 4; r++)
                    vals48[jl][(lhi * 4 + r) * 16 + lr] = d[r];
            }
        } else {
            __builtin_amdgcn_s_setprio(0);
        }
        int r1 = imax(imax(a0[0], a0[1]), a0[2]);
        int r2 = imax(imax(a0[3], a1[0]), a1[1]);
        int r3 = imax(imax(a1[2], a1[3]), a2[0]);
        int r4 = imax(imax(a2[1], a2[2]), a2[3]);
        vals[wave][jl][lane] = imax(imax(r1, r2), imax(r3, r4));
    };

    i32x4 A[2], B[2];
    loadT(A, 0);
    #pragma unroll 1
    for (int jj = 0; jj < 12; jj++) {
        loadT(B, 2 * jj + 1);
        compute(A, 2 * jj);
        loadT(A, 2 * jj + 2);
        compute(B, 2 * jj + 1);
    }
    compute(A, 24);
    __syncthreads();

    if (tid < WAVES * CH_T) {
        int g  = tid >> 4;
        int tl = tid & 15;
        float simg = pscale[ig * WAVES + g];
        const float* tf_s = tfs + tq * 400;
        float s = 0.f;
        #pragma unroll
        for (int l = 0; l < 25; l++) {
            int row = tl * 25 + l;
            int j = row >> 4;
            int r = row & 15;
            int m0 = imax(vals[g][j][r],      vals[g][j][r + 16]);
            int m1 = imax(vals[g][j][r + 32], vals[g][j][r + 48]);
            int mm = imax(imax(m0, m1), vals48[j][g * 16 + r]);
            s += (float)mm * tf_s[row];
        }
        int t = tq * CH_T + tl;
        int i = ig * WAVES + g;
        float val = s * simg / (float)text_length[t] * expf(logit_scale[0]);
        out[(size_t)i * NT + t] = val;
        out[(size_t)NI * NT + (size_t)t * NI + i] = val;
    }
}

__global__ __launch_bounds__(512, 4) void match_kernel(
    const char* __restrict__ tf3, const char* __restrict__ P2,
    const char* __restrict__ P48, const float* __restrict__ tfs,
    const float* __restrict__ pscale, const int* __restrict__ text_length,
    const float* __restrict__ logit_scale, float* __restrict__ out)
{
    __shared__ int vals[WAVES][CH_TILES][64];
    __shared__ int vals48[CH_TILES][128];
    match_body(blockIdx.x, tf3, P2, P48, tfs, pscale, text_length, logit_scale,
               out, vals, vals48);
}

// 8x-grid probe: identical body, folded wgid, dummy output.
__global__ __launch_bounds__(512, 4) void match_p8(
    const char* __restrict__ tf3, const char* __restrict__ P2,
    const char* __restrict__ P48, const float* __restrict__ tfs,
    const float* __restrict__ pscale, const int* __restrict__ text_length,
    const float* __restrict__ logit_scale, float* __restrict__ out)
{
    __shared__ int vals[WAVES][CH_TILES][64];
    __shared__ int vals48[CH_TILES][128];
    match_body(blockIdx.x & 511, tf3, P2, P48, tfs, pscale, text_length,
               logit_scale, out, vals, vals48);
}

extern "C" void kernel_launch(void* const* d_in, const int* in_sizes, int n_in,
                              void* d_out, int out_size, void* d_ws, size_t ws_size,
                              hipStream_t stream)
{
    const float* img  = (const float*)d_in[0];   // [256,128,7,7]
    const float* emb  = (const float*)d_in[1];   // [10000,128]
    const float* ls   = (const float*)d_in[2];   // scalar
    const int*   text = (const int*)d_in[3];     // [256,25]
    const int*   tlen = (const int*)d_in[4];     // [256]
    float* out = (float*)d_out;

    char* ws = (char*)d_ws;
    char*  tf3    = ws;                          //   819,200 B (i8 B-fragments)
    char*  P2     = ws + 819200;                 // 1,572,864 B (i8 A-fragments)
    char*  P48    = ws + 2392064;                //    65,536 B (packed patch-48)
    float* tfs    = (float*)(ws + 2457600);      //    25,600 B (per-word scales)
    float* pscale = (float*)(ws + 2483200);      //     1,024 B (per-image scales)
    float* dummy1 = (float*)(ws + 4194304);      //   524,288 B (1x re-run out)
    float* dummy8 = (float*)(ws + 8388608);      //   524,288 B (8x probe out)

    // ---- real path (byte-identical to round 12) ----
    prep_kernel<<<656, 256, 0, stream>>>(emb, text, img, tf3, P2, P48, tfs, pscale);
    match_kernel<<<512, 512, 0, stream>>>(tf3, P2, P48, tfs, pscale, tlen, ls, out);

    // ---- measurement probes ----
    // m1 via arithmetic: total = r12_total + m1 + m8 (+~0.5 launch gaps)
    match_kernel<<<512, 512, 0, stream>>>(tf3, P2, P48, tfs, pscale, tlen, ls, dummy1);
    // m8 via profile: longest dispatch -> owns the top-5, full counter set
    match_p8<<<4096, 512, 0, stream>>>(tf3, P2, P48, tfs, pscale, tlen, ls, dummy8);
}

// Round 15
// 39.814 us; speedup vs baseline: 2.8062x; 2.8062x over previous
//
#include <hip/hip_runtime.h>
#include <hip/hip_bf16.h>
#include <stdint.h>

#define NI 256
#define NT 256
#define NL 25
#define NE 128
#define NHW 49

#define CH_T 16            // texts per chunk
#define CH_TILES 25        // 16-row B tiles per chunk

typedef __attribute__((ext_vector_type(4))) int i32x4;

__device__ __forceinline__ int pack4(int q0, int q1, int q2, int q3) {
    return (q0 & 255) | ((q1 & 255) << 8) | ((q2 & 255) << 16) | ((q3 & 255) << 24);
}

// ---- Prep ----
// blocks 0..399: text tiles -> i8 B-fragments (identical to r12).
// blocks 400..655: image i -> per-image i8 quant, P2 A-fragments (6 frags),
//   P48 duty rows now per 4-image group (g4=i>>2, row=i&3).
__global__ __launch_bounds__(256) void prep_kernel(
    const float* __restrict__ emb, const int* __restrict__ text,
    const float* __restrict__ img,
    char* __restrict__ tf3, char* __restrict__ P2, char* __restrict__ P48,
    float* __restrict__ tfs, float* __restrict__ pscale)
{
    __shared__ float tile[NE * NHW];
    __shared__ float red[4];
    const int bid = blockIdx.x;
    const int tid = threadIdx.x;

    if (bid < 400) {
        int r   = tid >> 4;
        int sub = tid & 15;
        int row = bid * 16 + r;
        int tok = text[row];
        const float4* e4 = reinterpret_cast<const float4*>(emb + (size_t)tok * NE + sub * 8);
        float4 f0 = e4[0], f1 = e4[1];
        float m = fmaxf(fmaxf(fmaxf(fabsf(f0.x), fabsf(f0.y)), fmaxf(fabsf(f0.z), fabsf(f0.w))),
                        fmaxf(fmaxf(fabsf(f1.x), fabsf(f1.y)), fmaxf(fabsf(f1.z), fabsf(f1.w))));
        m = fmaxf(m, __shfl_xor(m, 1));
        m = fmaxf(m, __shfl_xor(m, 2));
        m = fmaxf(m, __shfl_xor(m, 4));
        m = fmaxf(m, __shfl_xor(m, 8));
        float s = (m > 0.f) ? 127.f / m : 0.f;
        if (sub == 0) tfs[row] = m / 127.f;
        int q0 = __float2int_rn(f0.x * s), q1 = __float2int_rn(f0.y * s);
        int q2 = __float2int_rn(f0.z * s), q3 = __float2int_rn(f0.w * s);
        int q4 = __float2int_rn(f1.x * s), q5 = __float2int_rn(f1.y * s);
        int q6 = __float2int_rn(f1.z * s), q7 = __float2int_rn(f1.w * s);
        int2 o = make_int2(pack4(q0, q1, q2, q3), pack4(q4, q5, q6, q7));
        int kh  = sub >> 3;
        int lhi = (sub >> 1) & 3;
        size_t addr = ((size_t)(bid * 2 + kh) * 64 + lhi * 16 + r) * 16 + (sub & 1) * 8;
        *reinterpret_cast<int2*>(tf3 + addr) = o;
    } else {
        int i = bid - 400;
        const float4* src4 = reinterpret_cast<const float4*>(img + (size_t)i * NE * NHW);
        float4* tile4 = reinterpret_cast<float4*>(tile);
        float lm = 0.f;
        for (int idx = tid; idx < NE * NHW / 4; idx += 256) {
            float4 v = src4[idx];
            tile4[idx] = v;
            lm = fmaxf(lm, fmaxf(fmaxf(fabsf(v.x), fabsf(v.y)),
                                 fmaxf(fabsf(v.z), fabsf(v.w))));
        }
        #pragma unroll
        for (int d = 1; d < 64; d <<= 1) lm = fmaxf(lm, __shfl_xor(lm, d));
        if ((tid & 63) == 0) red[tid >> 6] = lm;
        __syncthreads();                       // covers tile[] too
        float pmax = fmaxf(fmaxf(red[0], red[1]), fmaxf(red[2], red[3]));
        float s = (pmax > 0.f) ? 127.f / pmax : 0.f;
        if (tid == 0) pscale[i] = pmax / 127.f;

        for (int idx = tid; idx < 384; idx += 256) {
            int f = idx >> 6, lane = idx & 63;
            int mt = f >> 1, kh = f & 1;
            int lr = lane & 15, lhi = lane >> 4;
            int p = mt * 16 + lr;              // 0..47, all real
            int d[4];
            #pragma unroll
            for (int w = 0; w < 4; w++) {
                int e = kh * 64 + lhi * 16 + w * 4;
                d[w] = pack4(__float2int_rn(tile[(e + 0) * NHW + p] * s),
                             __float2int_rn(tile[(e + 1) * NHW + p] * s),
                             __float2int_rn(tile[(e + 2) * NHW + p] * s),
                             __float2int_rn(tile[(e + 3) * NHW + p] * s));
            }
            i32x4 o = { d[0], d[1], d[2], d[3] };
            *reinterpret_cast<i32x4*>(P2 + ((size_t)(i * 6 + f) * 64 + lane) * 16) = o;
        }
        // duty row: patch 48 of image i -> P48 group i>>2, A-row i&3
        if (tid < 8) {
            int kh = tid & 1, lhi = (tid >> 1) & 3;
            int g4 = i >> 2, r0 = i & 3;
            int d[4];
            #pragma unroll
            for (int w = 0; w < 4; w++) {
                int e = kh * 64 + lhi * 16 + w * 4;
                d[w] = pack4(__float2int_rn(tile[(e + 0) * NHW + 48] * s),
                             __float2int_rn(tile[(e + 1) * NHW + 48] * s),
                             __float2int_rn(tile[(e + 2) * NHW + 48] * s),
                             __float2int_rn(tile[(e + 3) * NHW + 48] * s));
            }
            i32x4 o = { d[0], d[1], d[2], d[3] };
            *reinterpret_cast<i32x4*>(P48 + ((size_t)(g4 * 2 + kh) * 64 + lhi * 16 + r0) * 16) = o;
        }
    }
}

// ---- Match: i8 MFMA, 4 images x 2 tile-parity waves, 16 KB LDS ----
// 1024 WGs = 64 image-groups (4 images) x 16 text-chunks; 4 WGs/CU = 32
// waves/CU (double r12's TLP). Wave (il, half): image il, tiles j%2==half.
// vals/vals48 stored as int16 (>>7) to fit the LDS diet.
__global__ __launch_bounds__(512, 8) void match_kernel(
    const char* __restrict__ tf3, const char* __restrict__ P2,
    const char* __restrict__ P48, const float* __restrict__ tfs,
    const float* __restrict__ pscale, const int* __restrict__ text_length,
    const float* __restrict__ logit_scale, float* __restrict__ out)
{
    __shared__ short vals[4][CH_TILES][64];   // 12800 B
    __shared__ short vals48[CH_TILES][64];    //  3200 B

    const int ig   = blockIdx.x & 63;    // image group (4 images)
    const int tq   = blockIdx.x >> 6;    // text chunk (16 texts = 25 tiles)
    const int tid  = threadIdx.x;
    const int wave = tid >> 6;
    const int il   = wave >> 1;          // image-local 0..3
    const int half = wave & 1;           // tile parity
    const int lane = tid & 63;
    const int lr   = lane & 15;
    const int lhi  = lane >> 4;

    const int img = ig * 4 + il;
    const i32x4* p2 = reinterpret_cast<const i32x4*>(P2) + (size_t)img * 6 * 64 + lane;
    i32x4 pf[6];
    #pragma unroll
    for (int f = 0; f < 6; f++) pf[f] = p2[f * 64];
    #pragma unroll
    for (int f = 0; f < 6; f++) asm volatile("" : "+v"(pf[f]));

    const i32x4* p48 = reinterpret_cast<const i32x4*>(P48) + (size_t)ig * 2 * 64 + lane;

    i32x4 zc = { 0, 0, 0, 0 };
    asm volatile("" : "+v"(zc));

    const char* tb = tf3 + (size_t)tq * CH_TILES * 2048 + lane * 16;

    auto loadT = [&](i32x4* T, int jl) {
        T[0] = *reinterpret_cast<const i32x4*>(tb + jl * 2048);
        T[1] = *reinterpret_cast<const i32x4*>(tb + jl * 2048 + 1024);
    };

    auto imax = [](int a, int b) { return a > b ? a : b; };

    auto compute = [&](const i32x4* T, int jl) {
        __builtin_amdgcn_s_setprio(1);
        i32x4 a0 = __builtin_amdgcn_mfma_i32_16x16x64_i8(pf[0], T[0], zc, 0, 0, 0);
        i32x4 a1 = __builtin_amdgcn_mfma_i32_16x16x64_i8(pf[2], T[0], zc, 0, 0, 0);
        i32x4 a2 = __builtin_amdgcn_mfma_i32_16x16x64_i8(pf[4], T[0], zc, 0, 0, 0);
        a0 = __builtin_amdgcn_mfma_i32_16x16x64_i8(pf[1], T[1], a0, 0, 0, 0);
        a1 = __builtin_amdgcn_mfma_i32_16x16x64_i8(pf[3], T[1], a1, 0, 0, 0);
        a2 = __builtin_amdgcn_mfma_i32_16x16x64_i8(pf[5], T[1], a2, 0, 0, 0);
        if ((jl & 7) == wave) {   // wave-uniform; parity-consistent with half
            i32x4 d = __builtin_amdgcn_mfma_i32_16x16x64_i8(p48[0],  T[0], zc, 0, 0, 0);
            d = __builtin_amdgcn_mfma_i32_16x16x64_i8(p48[64], T[1], d, 0, 0, 0);
            __builtin_amdgcn_s_setprio(0);
            if (lhi == 0) {       // D rows 0..3 = the group's 4 images
                #pragma unroll
                for (int r = 0; r < 4; r++)
                    vals48[jl][r * 16 + lr] = (short)(d[r] >> 7);
            }
        } else {
            __builtin_amdgcn_s_setprio(0);
        }
        int r1 = imax(imax(a0[0], a0[1]), a0[2]);
        int r2 = imax(imax(a0[3], a1[0]), a1[1]);
        int r3 = imax(imax(a1[2], a1[3]), a2[0]);
        int r4 = imax(imax(a2[1], a2[2]), a2[3]);
        int v = imax(imax(r1, r2), imax(r3, r4));
        vals[il][jl][lane] = (short)(v >> 7);
    };

    i32x4 A[2], B[2];
    loadT(A, half);
    int j = half;
    #pragma unroll 1
    for (int jj = 0; jj < 5; jj++) {
        loadT(B, j + 2);
        compute(A, j);
        loadT(A, j + 4);
        compute(B, j + 2);
        j += 4;
    }
    // j = half + 20
    if (half == 0) {     // tiles 20, 22, 24 (A holds 20)
        loadT(B, 22);
        compute(A, 20);
        loadT(A, 24);
        compute(B, 22);
        compute(A, 24);
    } else {             // tiles 21, 23 (A holds 21)
        loadT(B, 23);
        compute(A, 21);
        compute(B, 23);
    }
    __syncthreads();

    // Epilogue: int16 max over 4 lane-groups + duty row, descale (x128 for
    // the >>7), sum over l, scale; 64 outputs per WG.
    if (tid < 4 * CH_T) {
        int g  = tid >> 4;
        int tl = tid & 15;
        float simg = pscale[ig * 4 + g] * 128.f;
        const float* tf_s = tfs + tq * 400;
        float s = 0.f;
        #pragma unroll
        for (int l = 0; l < 25; l++) {
            int row = tl * 25 + l;          // text row within chunk, 0..399
            int jt = row >> 4;
            int r  = row & 15;
            int m0 = imax((int)vals[g][jt][r],      (int)vals[g][jt][r + 16]);
            int m1 = imax((int)vals[g][jt][r + 32], (int)vals[g][jt][r + 48]);
            int mm = imax(imax(m0, m1), (int)vals48[jt][g * 16 + r]);
            s += (float)mm * tf_s[row];
        }
        int t = tq * CH_T + tl;
        int i = ig * 4 + g;
        float val = s * simg / (float)text_length[t] * expf(logit_scale[0]);
        out[(size_t)i * NT + t] = val;                      // logits_per_image [I,T]
        out[(size_t)NI * NT + (size_t)t * NI + i] = val;    // logits_per_text  [T,I]
    }
}

extern "C" void kernel_launch(void* const* d_in, const int* in_sizes, int n_in,
                              void* d_out, int out_size, void* d_ws, size_t ws_size,
                              hipStream_t stream)
{
    const float* img  = (const float*)d_in[0];   // [256,128,7,7]
    const float* emb  = (const float*)d_in[1];   // [10000,128]
    const float* ls   = (const float*)d_in[2];   // scalar
    const int*   text = (const int*)d_in[3];     // [256,25]
    const int*   tlen = (const int*)d_in[4];     // [256]
    float* out = (float*)d_out;

    char* ws = (char*)d_ws;
    char*  tf3    = ws;                          //   819,200 B (i8 B-fragments)
    char*  P2     = ws + 819200;                 // 1,572,864 B (i8 A-fragments)
    char*  P48    = ws + 2392064;                //   131,072 B (4-row duty tiles)
    float* tfs    = (float*)(ws + 2523136);      //    25,600 B (per-word scales)
    float* pscale = (float*)(ws + 2548736);      //     1,024 B (per-image scales)

    prep_kernel<<<656, 256, 0, stream>>>(emb, text, img, tf3, P2, P48, tfs, pscale);
    match_kernel<<<1024, 512, 0, stream>>>(tf3, P2, P48, tfs, pscale, tlen, ls, out);
}

// Round 16
// 24.303 us; speedup vs baseline: 4.5972x; 1.6382x over previous
//
#include <hip/hip_runtime.h>
#include <hip/hip_bf16.h>
#include <stdint.h>

#define NI 256
#define NT 256
#define NL 25
#define NE 128
#define NHW 49

#define WAVES 8            // waves (=images) per match WG
#define CH_T 8             // texts per chunk (32 chunks)
#define NTIL 13            // 16-row tiles touched per chunk (last/first shared)

typedef __attribute__((ext_vector_type(4))) int i32x4;

__device__ __forceinline__ int pack4(int q0, int q1, int q2, int q3) {
    return (q0 & 255) | ((q1 & 255) << 8) | ((q2 & 255) << 16) | ((q3 & 255) << 24);
}

// ---- Prep (byte-identical to round 12) ----
__global__ __launch_bounds__(256) void prep_kernel(
    const float* __restrict__ emb, const int* __restrict__ text,
    const float* __restrict__ img,
    char* __restrict__ tf3, char* __restrict__ P2, char* __restrict__ P48,
    float* __restrict__ tfs, float* __restrict__ pscale)
{
    __shared__ float tile[NE * NHW];
    __shared__ float red[256];
    const int bid = blockIdx.x;
    const int tid = threadIdx.x;

    if (bid < 400) {
        int r   = tid >> 4;
        int sub = tid & 15;
        int row = bid * 16 + r;
        int tok = text[row];
        const float4* e4 = reinterpret_cast<const float4*>(emb + (size_t)tok * NE + sub * 8);
        float4 f0 = e4[0], f1 = e4[1];
        float m = fmaxf(fmaxf(fmaxf(fabsf(f0.x), fabsf(f0.y)), fmaxf(fabsf(f0.z), fabsf(f0.w))),
                        fmaxf(fmaxf(fabsf(f1.x), fabsf(f1.y)), fmaxf(fabsf(f1.z), fabsf(f1.w))));
        m = fmaxf(m, __shfl_xor(m, 1));
        m = fmaxf(m, __shfl_xor(m, 2));
        m = fmaxf(m, __shfl_xor(m, 4));
        m = fmaxf(m, __shfl_xor(m, 8));
        float s = (m > 0.f) ? 127.f / m : 0.f;
        if (sub == 0) tfs[row] = m / 127.f;
        int q0 = __float2int_rn(f0.x * s), q1 = __float2int_rn(f0.y * s);
        int q2 = __float2int_rn(f0.z * s), q3 = __float2int_rn(f0.w * s);
        int q4 = __float2int_rn(f1.x * s), q5 = __float2int_rn(f1.y * s);
        int q6 = __float2int_rn(f1.z * s), q7 = __float2int_rn(f1.w * s);
        int2 o = make_int2(pack4(q0, q1, q2, q3), pack4(q4, q5, q6, q7));
        int kh  = sub >> 3;
        int lhi = (sub >> 1) & 3;
        size_t addr = ((size_t)(bid * 2 + kh) * 64 + lhi * 16 + r) * 16 + (sub & 1) * 8;
        *reinterpret_cast<int2*>(tf3 + addr) = o;
    } else {
        int i = bid - 400;
        const float4* src4 = reinterpret_cast<const float4*>(img + (size_t)i * NE * NHW);
        float4* tile4 = reinterpret_cast<float4*>(tile);
        for (int idx = tid; idx < NE * NHW / 4; idx += 256) tile4[idx] = src4[idx];
        __syncthreads();
        float lm = 0.f;
        for (int idx = tid; idx < NE * NHW; idx += 256) lm = fmaxf(lm, fabsf(tile[idx]));
        red[tid] = lm;
        __syncthreads();
        #pragma unroll
        for (int st = 128; st > 0; st >>= 1) {
            if (tid < st) red[tid] = fmaxf(red[tid], red[tid + st]);
            __syncthreads();
        }
        float pmax = red[0];
        float s = (pmax > 0.f) ? 127.f / pmax : 0.f;
        if (tid == 0) pscale[i] = pmax / 127.f;

        for (int idx = tid; idx < 384; idx += 256) {
            int f = idx >> 6, lane = idx & 63;
            int mt = f >> 1, kh = f & 1;
            int lr = lane & 15, lhi = lane >> 4;
            int p = mt * 16 + lr;
            int d[4];
            #pragma unroll
            for (int w = 0; w < 4; w++) {
                int e = kh * 64 + lhi * 16 + w * 4;
                d[w] = pack4(__float2int_rn(tile[(e + 0) * NHW + p] * s),
                             __float2int_rn(tile[(e + 1) * NHW + p] * s),
                             __float2int_rn(tile[(e + 2) * NHW + p] * s),
                             __float2int_rn(tile[(e + 3) * NHW + p] * s));
            }
            i32x4 o = { d[0], d[1], d[2], d[3] };
            *reinterpret_cast<i32x4*>(P2 + ((size_t)(i * 6 + f) * 64 + lane) * 16) = o;
        }
        if (tid < 8) {
            int kh = tid & 1, lhi = (tid >> 1) & 3;
            int g = i >> 3, lr0 = i & 7;
            int d[4];
            #pragma unroll
            for (int w = 0; w < 4; w++) {
                int e = kh * 64 + lhi * 16 + w * 4;
                d[w] = pack4(__float2int_rn(tile[(e + 0) * NHW + 48] * s),
                             __float2int_rn(tile[(e + 1) * NHW + 48] * s),
                             __float2int_rn(tile[(e + 2) * NHW + 48] * s),
                             __float2int_rn(tile[(e + 3) * NHW + 48] * s));
            }
            i32x4 o = { d[0], d[1], d[2], d[3] };
            *reinterpret_cast<i32x4*>(P48 + ((size_t)(g * 2 + kh) * 64 + lhi * 16 + lr0) * 16) = o;
        }
    }
}

// ---- Match: i8 MFMA, r12 register structure, 13-tile chunks ----
// 1024 WGs = 32 image-groups (8 images) x 32 text-chunks (8 texts = 200
// rows spanning 13 global 16-row tiles; boundary tile shared with the
// neighbor chunk). Per-wave critical path halves (13 phases vs 25); int16
// vals -> 16.6 KB LDS -> 4 WGs/CU legal, 2-batch cross-WG pipelining.
__global__ __launch_bounds__(512, 4) void match_kernel(
    const char* __restrict__ tf3, const char* __restrict__ P2,
    const char* __restrict__ P48, const float* __restrict__ tfs,
    const float* __restrict__ pscale, const int* __restrict__ text_length,
    const float* __restrict__ logit_scale, float* __restrict__ out)
{
    __shared__ short vals[WAVES][NTIL][64];   // 13312 B, stored >>7
    __shared__ short vals48[NTIL][128];       //  3328 B

    const int ig   = blockIdx.x & 31;    // image group (8 images)
    const int tq   = blockIdx.x >> 5;    // text chunk (8 texts)
    const int tid  = threadIdx.x;
    const int wave = tid >> 6;
    const int lane = tid & 63;
    const int lr   = lane & 15;
    const int lhi  = lane >> 4;

    const int jg0 = (tq * 200) >> 4;     // first global tile of this chunk

    const int img = ig * WAVES + wave;
    const i32x4* p2 = reinterpret_cast<const i32x4*>(P2) + (size_t)img * 6 * 64 + lane;
    i32x4 pf[6];
    #pragma unroll
    for (int f = 0; f < 6; f++) pf[f] = p2[f * 64];
    #pragma unroll
    for (int f = 0; f < 6; f++) asm volatile("" : "+v"(pf[f]));

    const i32x4* p48 = reinterpret_cast<const i32x4*>(P48) + (size_t)ig * 2 * 64 + lane;

    i32x4 zc = { 0, 0, 0, 0 };
    asm volatile("" : "+v"(zc));

    const char* tb = tf3 + (size_t)jg0 * 2048 + lane * 16;

    auto loadT = [&](i32x4* T, int jl) {
        T[0] = *reinterpret_cast<const i32x4*>(tb + jl * 2048);
        T[1] = *reinterpret_cast<const i32x4*>(tb + jl * 2048 + 1024);
    };

    auto imax = [](int a, int b) { return a > b ? a : b; };

    auto compute = [&](const i32x4* T, int jl) {
        __builtin_amdgcn_s_setprio(1);
        i32x4 a0 = __builtin_amdgcn_mfma_i32_16x16x64_i8(pf[0], T[0], zc, 0, 0, 0);
        i32x4 a1 = __builtin_amdgcn_mfma_i32_16x16x64_i8(pf[2], T[0], zc, 0, 0, 0);
        i32x4 a2 = __builtin_amdgcn_mfma_i32_16x16x64_i8(pf[4], T[0], zc, 0, 0, 0);
        a0 = __builtin_amdgcn_mfma_i32_16x16x64_i8(pf[1], T[1], a0, 0, 0, 0);
        a1 = __builtin_amdgcn_mfma_i32_16x16x64_i8(pf[3], T[1], a1, 0, 0, 0);
        a2 = __builtin_amdgcn_mfma_i32_16x16x64_i8(pf[5], T[1], a2, 0, 0, 0);
        if ((jl & 7) == wave) {
            i32x4 d = __builtin_amdgcn_mfma_i32_16x16x64_i8(p48[0],  T[0], zc, 0, 0, 0);
            d = __builtin_amdgcn_mfma_i32_16x16x64_i8(p48[64], T[1], d, 0, 0, 0);
            __builtin_amdgcn_s_setprio(0);
            if (lhi < 2) {
                #pragma unroll
                for (int r = 0; r < 4; r++)
                    vals48[jl][(lhi * 4 + r) * 16 + lr] = (short)(d[r] >> 7);
            }
        } else {
            __builtin_amdgcn_s_setprio(0);
        }
        int r1 = imax(imax(a0[0], a0[1]), a0[2]);
        int r2 = imax(imax(a0[3], a1[0]), a1[1]);
        int r3 = imax(imax(a1[2], a1[3]), a2[0]);
        int r4 = imax(imax(a2[1], a2[2]), a2[3]);
        vals[wave][jl][lane] = (short)(imax(imax(r1, r2), imax(r3, r4)) >> 7);
    };

    i32x4 A[2], B[2];
    loadT(A, 0);
    #pragma unroll 1
    for (int jj = 0; jj < 6; jj++) {
        loadT(B, 2 * jj + 1);
        compute(A, 2 * jj);
        loadT(A, 2 * jj + 2);
        compute(B, 2 * jj + 1);
    }
    compute(A, 12);
    __syncthreads();

    // Epilogue: int max over 4 lane-groups + duty row, descale (x128 for
    // the >>7), length-25 sum, scale; 64 outputs (8 images x 8 texts).
    if (tid < WAVES * CH_T) {
        int g  = tid >> 3;
        int tl = tid & 7;
        int t  = tq * CH_T + tl;
        float simg = pscale[ig * WAVES + g] * 128.f;
        float s = 0.f;
        #pragma unroll
        for (int l = 0; l < 25; l++) {
            int row = t * 25 + l;           // global text row
            int jt  = (row >> 4) - jg0;     // local tile 0..12
            int r   = row & 15;
            int m0 = imax((int)vals[g][jt][r],      (int)vals[g][jt][r + 16]);
            int m1 = imax((int)vals[g][jt][r + 32], (int)vals[g][jt][r + 48]);
            int mm = imax(imax(m0, m1), (int)vals48[jt][g * 16 + r]);
            s += (float)mm * tfs[row];
        }
        int i = ig * WAVES + g;
        float val = s * simg / (float)text_length[t] * expf(logit_scale[0]);
        out[(size_t)i * NT + t] = val;                      // logits_per_image [I,T]
        out[(size_t)NI * NT + (size_t)t * NI + i] = val;    // logits_per_text  [T,I]
    }
}

extern "C" void kernel_launch(void* const* d_in, const int* in_sizes, int n_in,
                              void* d_out, int out_size, void* d_ws, size_t ws_size,
                              hipStream_t stream)
{
    const float* img  = (const float*)d_in[0];   // [256,128,7,7]
    const float* emb  = (const float*)d_in[1];   // [10000,128]
    const float* ls   = (const float*)d_in[2];   // scalar
    const int*   text = (const int*)d_in[3];     // [256,25]
    const int*   tlen = (const int*)d_in[4];     // [256]
    float* out = (float*)d_out;

    char* ws = (char*)d_ws;
    char*  tf3    = ws;                          //   819,200 B (i8 B-fragments)
    char*  P2     = ws + 819200;                 // 1,572,864 B (i8 A-fragments)
    char*  P48    = ws + 2392064;                //    65,536 B (packed patch-48)
    float* tfs    = (float*)(ws + 2457600);      //    25,600 B (per-word scales)
    float* pscale = (float*)(ws + 2483200);      //     1,024 B (per-image scales)

    prep_kernel<<<656, 256, 0, stream>>>(emb, text, img, tf3, P2, P48, tfs, pscale);
    match_kernel<<<1024, 512, 0, stream>>>(tf3, P2, P48, tfs, pscale, tlen, ls, out);
}

// Round 17
// 23.147 us; speedup vs baseline: 4.8269x; 1.0500x over previous
//
#include <hip/hip_runtime.h>
#include <hip/hip_bf16.h>
#include <stdint.h>

#define NI 256
#define NT 256
#define NL 25
#define NE 128
#define NHW 49
#define NTL (NT*NL)   // 6400

#define WAVES 8            // waves (=images) per match WG
#define CH_T 16            // texts per chunk
#define CH_TILES 25        // 16-row B tiles per chunk

typedef __attribute__((ext_vector_type(4))) int i32x4;

__device__ __forceinline__ int pack4(int q0, int q1, int q2, int q3) {
    return (q0 & 255) | ((q1 & 255) << 8) | ((q2 & 255) << 16) | ((q3 & 255) << 24);
}

// ---- Prep ----
// blocks 0..399 (text tile j): per-word i8 quant + B-fragment order (K=64):
//   chunk c=(j*2+kh)*64+lane (16B): byte b = q(emb[text[j*16+lr]][kh*64+lhi*16+b]),
//   scale tfs[row] = rowmax/127 (0 for zero rows -> sims exactly 0).
// blocks 400..655 (image i): per-image i8 quant. P2 A-fragments:
//   chunk (i*6+m*2+kh)*64+lane: byte b = q(img patch m*16+lr, elem kh*64+lhi*16+b).
//   Also writes its row of the packed patch-48 duty tile P48 and pscale[i].
__global__ __launch_bounds__(256) void prep_kernel(
    const float* __restrict__ emb, const int* __restrict__ text,
    const float* __restrict__ img,
    char* __restrict__ tf3, char* __restrict__ P2, char* __restrict__ P48,
    float* __restrict__ tfs, float* __restrict__ pscale)
{
    __shared__ float tile[NE * NHW];
    __shared__ float red[256];
    const int bid = blockIdx.x;
    const int tid = threadIdx.x;

    if (bid < 400) {
        // ---- text tile: 16 rows x 128 elems; thread = (row r, sub) ----
        int r   = tid >> 4;
        int sub = tid & 15;
        int row = bid * 16 + r;
        int tok = text[row];
        const float4* e4 = reinterpret_cast<const float4*>(emb + (size_t)tok * NE + sub * 8);
        float4 f0 = e4[0], f1 = e4[1];
        float m = fmaxf(fmaxf(fmaxf(fabsf(f0.x), fabsf(f0.y)), fmaxf(fabsf(f0.z), fabsf(f0.w))),
                        fmaxf(fmaxf(fabsf(f1.x), fabsf(f1.y)), fmaxf(fabsf(f1.z), fabsf(f1.w))));
        // row max across the 16 threads of this row (lanes share a 16-group)
        m = fmaxf(m, __shfl_xor(m, 1));
        m = fmaxf(m, __shfl_xor(m, 2));
        m = fmaxf(m, __shfl_xor(m, 4));
        m = fmaxf(m, __shfl_xor(m, 8));
        float s = (m > 0.f) ? 127.f / m : 0.f;
        if (sub == 0) tfs[row] = m / 127.f;
        int q0 = __float2int_rn(f0.x * s), q1 = __float2int_rn(f0.y * s);
        int q2 = __float2int_rn(f0.z * s), q3 = __float2int_rn(f0.w * s);
        int q4 = __float2int_rn(f1.x * s), q5 = __float2int_rn(f1.y * s);
        int q6 = __float2int_rn(f1.z * s), q7 = __float2int_rn(f1.w * s);
        int2 o = make_int2(pack4(q0, q1, q2, q3), pack4(q4, q5, q6, q7));
        int kh  = sub >> 3;
        int lhi = (sub >> 1) & 3;
        size_t addr = ((size_t)(bid * 2 + kh) * 64 + lhi * 16 + r) * 16 + (sub & 1) * 8;
        *reinterpret_cast<int2*>(tf3 + addr) = o;
    } else {
        // ---- image block ----
        int i = bid - 400;
        const float4* src4 = reinterpret_cast<const float4*>(img + (size_t)i * NE * NHW);
        float4* tile4 = reinterpret_cast<float4*>(tile);
        for (int idx = tid; idx < NE * NHW / 4; idx += 256) tile4[idx] = src4[idx];
        __syncthreads();
        float lm = 0.f;
        for (int idx = tid; idx < NE * NHW; idx += 256) lm = fmaxf(lm, fabsf(tile[idx]));
        red[tid] = lm;
        __syncthreads();
        #pragma unroll
        for (int st = 128; st > 0; st >>= 1) {
            if (tid < st) red[tid] = fmaxf(red[tid], red[tid + st]);
            __syncthreads();
        }
        float pmax = red[0];
        float s = (pmax > 0.f) ? 127.f / pmax : 0.f;
        if (tid == 0) pscale[i] = pmax / 127.f;

        // P2 fragments: 6 frags (m<3, kh<2) x 64 lanes, 16B each
        for (int idx = tid; idx < 384; idx += 256) {
            int f = idx >> 6, lane = idx & 63;
            int mt = f >> 1, kh = f & 1;
            int lr = lane & 15, lhi = lane >> 4;
            int p = mt * 16 + lr;              // 0..47, all real
            int d[4];
            #pragma unroll
            for (int w = 0; w < 4; w++) {
                int e = kh * 64 + lhi * 16 + w * 4;
                d[w] = pack4(__float2int_rn(tile[(e + 0) * NHW + p] * s),
                             __float2int_rn(tile[(e + 1) * NHW + p] * s),
                             __float2int_rn(tile[(e + 2) * NHW + p] * s),
                             __float2int_rn(tile[(e + 3) * NHW + p] * s));
            }
            i32x4 o = { d[0], d[1], d[2], d[3] };
            *reinterpret_cast<i32x4*>(P2 + ((size_t)(i * 6 + f) * 64 + lane) * 16) = o;
        }
        // duty-tile row: patch 48 of this image -> P48 group g=i>>3, row lr0=i&7
        if (tid < 8) {
            int kh = tid & 1, lhi = (tid >> 1) & 3;
            int g = i >> 3, lr0 = i & 7;
            int d[4];
            #pragma unroll
            for (int w = 0; w < 4; w++) {
                int e = kh * 64 + lhi * 16 + w * 4;
                d[w] = pack4(__float2int_rn(tile[(e + 0) * NHW + 48] * s),
                             __float2int_rn(tile[(e + 1) * NHW + 48] * s),
                             __float2int_rn(tile[(e + 2) * NHW + 48] * s),
                             __float2int_rn(tile[(e + 3) * NHW + 48] * s));
            }
            i32x4 o = { d[0], d[1], d[2], d[3] };
            *reinterpret_cast<i32x4*>(P48 + ((size_t)(g * 2 + kh) * 64 + lhi * 16 + lr0) * 16) = o;
        }
    }
}

// ---- Match: i8 MFMA GEMM (swapped operands) + int max + descaled sum ----
// 512 WGs = 32 image-groups (8 images) x 16 text-chunks; wave = 1 image.
// 3 m-tiles x 2 K-halves = 6 mfma_i32_16x16x64_i8 per 16-text tile (+duty).
// Max over patches in int (per-(image,word) positive scale commutes);
// descale once per (t,l) in the epilogue.
__global__ __launch_bounds__(512, 4) void match_kernel(
    const char* __restrict__ tf3,
    const char* __restrict__ P2,
    const char* __restrict__ P48,
    const float* __restrict__ tfs,
    const float* __restrict__ pscale,
    const int* __restrict__ text_length,
    const float* __restrict__ logit_scale,
    float* __restrict__ out)
{
    __shared__ int vals[WAVES][CH_TILES][64];   // per-lane 12-patch int max
    __shared__ int vals48[CH_TILES][128];       // [j][imgrow*16+textcol] patch-48 i32

    const int ig   = blockIdx.x & 31;    // image group (8 images)
    const int tq   = blockIdx.x >> 5;    // text chunk (16 texts = 25 tiles)
    const int tid  = threadIdx.x;
    const int wave = tid >> 6;
    const int lane = tid & 63;
    const int lr   = lane & 15;
    const int lhi  = lane >> 4;

    // pfrag: 6 coalesced 1KB loads from fragment-order P2, pinned resident
    const int img = ig * WAVES + wave;
    const i32x4* p2 = reinterpret_cast<const i32x4*>(P2) + (size_t)img * 6 * 64 + lane;
    i32x4 pf[6];
    #pragma unroll
    for (int f = 0; f < 6; f++) pf[f] = p2[f * 64];
    #pragma unroll
    for (int f = 0; f < 6; f++) asm volatile("" : "+v"(pf[f]));

    const i32x4* p48 = reinterpret_cast<const i32x4*>(P48) + (size_t)ig * 2 * 64 + lane;

    i32x4 zc = { 0, 0, 0, 0 };
    asm volatile("" : "+v"(zc));

    // B stream: tile jl at +jl*2048, K-half kh at +kh*1024, lane*16
    const char* tb = tf3 + (size_t)tq * CH_TILES * 2048 + lane * 16;

    auto loadT = [&](i32x4* T, int jl) {
        T[0] = *reinterpret_cast<const i32x4*>(tb + jl * 2048);
        T[1] = *reinterpret_cast<const i32x4*>(tb + jl * 2048 + 1024);
    };

    auto imax = [](int a, int b) { return a > b ? a : b; };

    auto compute = [&](const i32x4* T, int jl) {
        __builtin_amdgcn_s_setprio(1);
        i32x4 a0 = __builtin_amdgcn_mfma_i32_16x16x64_i8(pf[0], T[0], zc, 0, 0, 0);
        i32x4 a1 = __builtin_amdgcn_mfma_i32_16x16x64_i8(pf[2], T[0], zc, 0, 0, 0);
        i32x4 a2 = __builtin_amdgcn_mfma_i32_16x16x64_i8(pf[4], T[0], zc, 0, 0, 0);
        a0 = __builtin_amdgcn_mfma_i32_16x16x64_i8(pf[1], T[1], a0, 0, 0, 0);
        a1 = __builtin_amdgcn_mfma_i32_16x16x64_i8(pf[3], T[1], a1, 0, 0, 0);
        a2 = __builtin_amdgcn_mfma_i32_16x16x64_i8(pf[5], T[1], a2, 0, 0, 0);
        if ((jl & 7) == wave) {
            // packed patch-48 tile: A rows = this group's 8 images (L1-hot)
            i32x4 d = __builtin_amdgcn_mfma_i32_16x16x64_i8(p48[0],  T[0], zc, 0, 0, 0);
            d = __builtin_amdgcn_mfma_i32_16x16x64_i8(p48[64], T[1], d, 0, 0, 0);
            __builtin_amdgcn_s_setprio(0);
            if (lhi < 2) {
                #pragma unroll
                for (int r = 0; r < 4; r++)
                    vals48[jl][(lhi * 4 + r) * 16 + lr] = d[r];   // row=image, col=text
            }
        } else {
            __builtin_amdgcn_s_setprio(0);
        }
        // per-lane int max over its 12 patches (same image, same text col)
        int r1 = imax(imax(a0[0], a0[1]), a0[2]);
        int r2 = imax(imax(a0[3], a1[0]), a1[1]);
        int r3 = imax(imax(a1[2], a1[3]), a2[0]);
        int r4 = imax(imax(a2[1], a2[2]), a2[3]);
        vals[wave][jl][lane] = imax(imax(r1, r2), imax(r3, r4));
    };

    i32x4 A[2], B[2];
    loadT(A, 0);
    #pragma unroll 1
    for (int jj = 0; jj < 12; jj++) {
        loadT(B, 2 * jj + 1);
        compute(A, 2 * jj);
        loadT(A, 2 * jj + 2);
        compute(B, 2 * jj + 1);
    }
    compute(A, 24);
    __syncthreads();

    // Epilogue: int max over 4 lane-groups + duty row, descale, sum, scale.
    if (tid < WAVES * CH_T) {
        int g  = tid >> 4;
        int tl = tid & 15;
        float simg = pscale[ig * WAVES + g];
        const float* tf_s = tfs + tq * 400;
        float s = 0.f;
        #pragma unroll
        for (int l = 0; l < 25; l++) {
            int row = tl * 25 + l;          // text row within chunk, 0..399
            int j = row >> 4;
            int r = row & 15;
            int m0 = imax(vals[g][j][r],      vals[g][j][r + 16]);
            int m1 = imax(vals[g][j][r + 32], vals[g][j][r + 48]);
            int mm = imax(imax(m0, m1), vals48[j][g * 16 + r]);
            s += (float)mm * tf_s[row];
        }
        int t = tq * CH_T + tl;
        int i = ig * WAVES + g;
        float val = s * simg / (float)text_length[t] * expf(logit_scale[0]);
        out[(size_t)i * NT + t] = val;                      // logits_per_image [I,T]
        out[(size_t)NI * NT + (size_t)t * NI + i] = val;    // logits_per_text  [T,I]
    }
}

extern "C" void kernel_launch(void* const* d_in, const int* in_sizes, int n_in,
                              void* d_out, int out_size, void* d_ws, size_t ws_size,
                              hipStream_t stream)
{
    const float* img  = (const float*)d_in[0];   // [256,128,7,7]
    const float* emb  = (const float*)d_in[1];   // [10000,128]
    const float* ls   = (const float*)d_in[2];   // scalar
    const int*   text = (const int*)d_in[3];     // [256,25]
    const int*   tlen = (const int*)d_in[4];     // [256]
    float* out = (float*)d_out;

    char* ws = (char*)d_ws;
    char*  tf3    = ws;                          //   819,200 B (i8 B-fragments)
    char*  P2     = ws + 819200;                 // 1,572,864 B (i8 A-fragments)
    char*  P48    = ws + 2392064;                //    65,536 B (packed patch-48)
    float* tfs    = (float*)(ws + 2457600);      //    25,600 B (per-word scales)
    float* pscale = (float*)(ws + 2483200);      //     1,024 B (per-image scales)

    prep_kernel<<<656, 256, 0, stream>>>(emb, text, img, tf3, P2, P48, tfs, pscale);
    match_kernel<<<512, 512, 0, stream>>>(tf3, P2, P48, tfs, pscale, tlen, ls, out);
}